// Round 15
// baseline (49.345 us; speedup 1.0000x reference)
//
#include <hip/hip_runtime.h>
#include <math.h>

#define B_    8
#define C_    128
#define L_    8192
#define O_    128
#define POS_  10
#define CHIN  798
#define CH_   266          // 128 direct + 128 gathered + 10 penc
#define GSTR  128          // G row stride (direct channels only)
#define NCH   9            // chunks of 32 channels (288 padded)
#define TL2   128          // l-tile for GEMM (512 blocks -> 2 resident/CU)
#define G_ELEMS  ((size_t)B_ * L_ * GSTR)     // f16: 16.78 MB
#define WT_ELEMS ((size_t)3 * NCH * O_ * 32)  // f16: 221 KB

typedef _Float16 half8 __attribute__((ext_vector_type(8)));
typedef short short8 __attribute__((ext_vector_type(8)));
typedef float f32x4  __attribute__((ext_vector_type(4)));

// ---------------------------------------------------------------------------
// mask dtype detect core: 256 threads scan 64 KB; mflag 1=byte,0=i32,2=i64
// ---------------------------------------------------------------------------
__device__ __forceinline__ void detect_core(const uint4* __restrict__ m,
                                            int* __restrict__ mflag, int tid) {
    __shared__ int s[2];
    if (tid < 2) s[tid] = 0;
    __syncthreads();
    unsigned sub = 0, mid = 0;
    #pragma unroll
    for (int k = 0; k < 16; ++k) {
        uint4 w = m[tid + k * 256];              // 4096 * 16B = 64 KB
        sub |= (w.x | w.y | w.z | w.w) & 0xFFFFFF00u;
        mid |= (w.y | w.w) & 0x000000FFu;
    }
    unsigned long long bs = __ballot(sub != 0);
    unsigned long long bm = __ballot(mid != 0);
    if ((tid & 63) == 0) {
        if (bs) atomicOr(&s[0], 1);
        if (bm) atomicOr(&s[1], 1);
    }
    __syncthreads();
    if (tid == 0) mflag[0] = s[0] ? 1 : (s[1] ? 0 : 2);
}

__global__ void detect_kernel(const uint4* __restrict__ m, int* __restrict__ mflag) {
    detect_core(m, mflag, threadIdx.x);
}

// ---------------------------------------------------------------------------
// prep: blocks [0,2048): transpose inputs[b,c,l] f32 -> G[b,l,c] f16 (c<128)
//       blocks [2048,2480): Wt2[t][ch][o][cc] = (f16) W[o][3*(ch*32+cc)+t]
//       block 2480: mask dtype detect
// ---------------------------------------------------------------------------
__global__ __launch_bounds__(256, 4)
void prep_kernel(const float* __restrict__ inputs, const float* __restrict__ W,
                 const uint4* __restrict__ maskv,
                 _Float16* __restrict__ G, _Float16* __restrict__ Wt2,
                 int* __restrict__ mflag) {
    __shared__ float tile[64][65];
    const int bid = blockIdx.x;
    const int tid = threadIdx.x;

    if (bid == 2480) { detect_core(maskv, mflag, tid); return; }

    if (bid >= 2048) {   // Wt2 prep: 432 blocks * 256 = 110,592 elems exact
        int idx = (bid - 2048) * 256 + tid;
        int cc  = idx & 31;
        int o   = (idx >> 5) & 127;
        int tch = idx >> 12;          // 0..26
        int ch  = tch % 9;
        int t   = tch / 9;
        int cg  = ch * 32 + cc;
        Wt2[idx] = (cg < CH_) ? (_Float16)W[o * CHIN + 3 * cg + t] : (_Float16)0.f;
        return;
    }

    const int b  = bid & 7;          // b -> XCD affinity
    const int r  = bid >> 3;
    const int c0 = (r & 1) * 64;
    const int l0 = (r >> 1) * 64;
    const int ty = tid >> 6, tx = tid & 63;

    #pragma unroll
    for (int it = 0; it < 16; ++it) {
        int cl = it * 4 + ty;
        tile[cl][tx] = inputs[((size_t)(b * C_ + c0 + cl)) * L_ + l0 + tx];
    }
    __syncthreads();
    const int cp = (tid & 31) * 2;
    const int lr = tid >> 5;          // 0..7
    #pragma unroll
    for (int it = 0; it < 8; ++it) {
        int ll = it * 8 + lr;
        _Float16 pair[2] = {(_Float16)tile[cp][ll], (_Float16)tile[cp + 1][ll]};
        *(unsigned*)&G[((size_t)(b * L_ + l0 + ll)) * GSTR + c0 + cp] = *(unsigned*)pair;
    }
}

// ---------------------------------------------------------------------------
// K2: f16 MFMA GEMM. grid 512 flat (b = bid&7 -> XCD; 2 blocks/CU). 256 thr =
// 4 waves (2o x 2l), wave tile 64o x 64l.
// A (Wt2): REGISTER double-buffer, 12 coalesced 1KB wave-loads issued one
//   chunk ahead (L1/L2-resident; no LDS round-trip, no As staging).
// B: LDS double-buffer (2 x 132 x 40), reg-prefetch one chunk ahead, ONE
//   barrier per chunk. ch 0-3: direct G rows; 4-7: G[conn]; 8: inline penc.
// __launch_bounds__(256) -> VGPR cap 256 (no spill); 2 blocks/CU by VGPR.
// ---------------------------------------------------------------------------
__global__ __launch_bounds__(256)
void k2_gemm(const _Float16* __restrict__ G, const _Float16* __restrict__ Wt2,
             const int* __restrict__ conn,
             const unsigned char* __restrict__ mask,
             const float* __restrict__ bias,
             float* __restrict__ out,
             const int* __restrict__ mflag_p) {
    __shared__ _Float16 Bs[2][132][40];   // 21.1 KB, rows l0-1 .. l0+128
    __shared__ int conn_s[130];

    const int bid = blockIdx.x;           // 0..511
    const int b   = bid & 7;
    const int l0  = (bid >> 3) * TL2;
    const int tid  = threadIdx.x;
    const int wave = tid >> 6;            // 0..3
    const int lane = tid & 63;
    const int wo = wave & 1;
    const int wl = wave >> 1;
    const int g  = lane >> 4;
    const int ln = lane & 15;

    const _Float16* gb = G + (size_t)b * L_ * GSTR;

    for (int j = tid; j < TL2 + 2; j += 256) {
        int l_ = l0 - 1 + j;
        conn_s[j] = ((unsigned)l_ < (unsigned)L_) ? conn[b * L_ + l_] : 0;
    }

    // B loader: q in [0,520): cb=q&3 (8-f16 block), j=q>>2 (row 0..129)
    auto bload = [&](int ch, int q) -> short8 {
        int cb = q & 3, j = q >> 2;
        int l_ = l0 - 1 + j;
        short8 v = (short8)0;
        if ((unsigned)l_ < (unsigned)L_) {
            if (ch < 4) {
                v = *(const short8*)&gb[(size_t)l_ * GSTR + ch * 32 + cb * 8];
            } else if (ch < 8) {
                int cj = conn_s[j];
                v = *(const short8*)&gb[(size_t)cj * GSTR + (ch - 4) * 32 + cb * 8];
            } else if (cb < 2) {
                float d = (float)(l_ - conn_s[j]);
                _Float16 h[8];
                #pragma unroll
                for (int e = 0; e < 8; ++e) {
                    int p = cb * 8 + e;
                    h[e] = (p < POS_) ? (_Float16)sinf(((float)(1 << p)) * d / 1000.0f)
                                      : (_Float16)0.f;
                }
                v = *(short8*)h;
            }
        }
        return v;
    };
    auto bwrite = [&](short8 s, int q, int buf) {
        int cb = q & 3, j = q >> 2;
        *(short8*)&Bs[buf][j][cb * 8] = s;
    };

    // A-fragment register load: per (t,m) one coalesced 1KB wave-load
#define ALOADR(DST, CH) { _Pragma("unroll") for (int t_ = 0; t_ < 3; ++t_) \
        _Pragma("unroll") for (int m_ = 0; m_ < 4; ++m_) \
            DST[t_][m_] = *(const half8*)&Wt2[((size_t)((t_ * NCH + (CH)) * O_ + wo * 64 + m_ * 16 + ln)) * 32 + g * 8]; }

#define BLOADR(CH) { s0 = bload((CH), tid); s1 = bload((CH), tid + 256); \
        if (tid < 8) s2 = bload((CH), 512 + tid); }

#define BWR(BUF) { bwrite(s0, tid, (BUF)); bwrite(s1, tid + 256, (BUF)); \
        if (tid < 8) bwrite(s2, 512 + tid, (BUF)); }

#define COMPUTE(AUSE, BUF) { _Pragma("unroll") for (int t_ = 0; t_ < 3; ++t_) { \
        half8 bf_[4]; \
        _Pragma("unroll") for (int n_ = 0; n_ < 4; ++n_) \
            bf_[n_] = *(const half8*)&Bs[BUF][wl * 64 + n_ * 16 + ln + t_][8 * g]; \
        _Pragma("unroll") for (int m_ = 0; m_ < 4; ++m_) \
            _Pragma("unroll") for (int n_ = 0; n_ < 4; ++n_) \
                acc[m_][n_] = __builtin_amdgcn_mfma_f32_16x16x32_f16(AUSE[t_][m_], bf_[n_], acc[m_][n_], 0, 0, 0); } }

    f32x4 acc[4][4];
    #pragma unroll
    for (int m = 0; m < 4; ++m)
        #pragma unroll
        for (int n = 0; n < 4; ++n) acc[m][n] = (f32x4)0.f;

    half8 A0[3][4], A1[3][4];
    short8 s0, s1, s2;

    // prologue: A(ch0) regs + B(ch0) -> Bs[0]  (ch0 is direct rows, no conn)
    ALOADR(A0, 0);
    BLOADR(0);
    BWR(0);
    __syncthreads();   // publishes Bs[0] and conn_s

    // main: 4 unrolled pairs; compute ch with A0/A1 alternating, 1 barrier/chunk
    for (int ch = 0; ch < 8; ch += 2) {
        ALOADR(A1, ch + 1);
        BLOADR(ch + 1);
        COMPUTE(A0, 0);
        BWR(1);
        __syncthreads();

        ALOADR(A0, ch + 2);        // ch+2 <= 8
        BLOADR(ch + 2);
        COMPUTE(A1, 1);
        BWR(0);
        __syncthreads();
    }
    COMPUTE(A0, 0);                // chunk 8 (penc)

    // epilogue: D col = lane&15 (l), row = g*4+r (o) within frag
    const int mflag = mflag_p[0];
    float mv[4];
    #pragma unroll
    for (int n = 0; n < 4; ++n) {
        int l = l0 + wl * 64 + n * 16 + ln;
        int idx = b * L_ + l;
        if (mflag == 1)      mv[n] = mask[idx] ? 1.f : 0.f;
        else if (mflag == 0) mv[n] = ((const int*)mask)[idx] ? 1.f : 0.f;
        else                 mv[n] = ((const int*)mask)[2 * idx] ? 1.f : 0.f;
    }
    #pragma unroll
    for (int m = 0; m < 4; ++m) {
        #pragma unroll
        for (int r = 0; r < 4; ++r) {
            int o = wo * 64 + m * 16 + g * 4 + r;
            float bo = bias[o];
            #pragma unroll
            for (int n = 0; n < 4; ++n) {
                int l = l0 + wl * 64 + n * 16 + ln;
                out[((size_t)(b * O_ + o)) * L_ + l] = (acc[m][n][r] + bo) * mv[n];
            }
        }
    }
#undef ALOADR
#undef BLOADR
#undef BWR
#undef COMPUTE
}

// ---------------------------------------------------------------------------
// Fallback (fp32 vector path) if workspace too small
// ---------------------------------------------------------------------------
__global__ __launch_bounds__(256, 2)
void cc_fallback_kernel(const float* __restrict__ inputs,
                        const int* __restrict__ conn,
                        const unsigned char* __restrict__ mask,
                        const float* __restrict__ W,
                        const float* __restrict__ bias,
                        float* __restrict__ out,
                        const int* __restrict__ mflag_p) {
    __shared__ int   conn_s[130];
    __shared__ float feat_s[16][132];
    __shared__ float Ws[48][136];

    const int b   = blockIdx.y;
    const int l0  = blockIdx.x * 128;
    const int tid = threadIdx.x;
    const int ot  = tid >> 4;
    const int lt  = tid & 15;
    const int o0  = ot * 8;
    const int ll  = lt * 8;

    for (int j = tid; j < 130; j += 256) {
        int lg = l0 - 1 + j;
        conn_s[j] = ((unsigned)lg < (unsigned)L_) ? conn[b * L_ + lg] : -1;
    }
    float acc[8][8];
    #pragma unroll
    for (int i = 0; i < 8; ++i)
        #pragma unroll
        for (int j = 0; j < 8; ++j) acc[i][j] = 0.f;

    const int tc = ot, tj = lt;
    for (int chunk = 0; chunk < 17; ++chunk) {
        const int CN  = (chunk < 16) ? 16 : POS_;
        const int cg0 = chunk * 16;
        const int col0 = 3 * cg0;
        __syncthreads();
        {
            const int nw = O_ * CN * 3;
            for (int idx = tid; idx < nw; idx += 256) {
                int o = idx & 127, kk = idx >> 7;
                Ws[kk][o] = W[o * CHIN + col0 + kk];
            }
        }
        if (chunk < 8) {
            const float* src = inputs + ((size_t)b * C_ + (cg0 + tc)) * L_;
            for (int j = tj; j < 130; j += 16) {
                int lg = l0 - 1 + j;
                feat_s[tc][j] = ((unsigned)lg < (unsigned)L_) ? src[lg] : 0.f;
            }
        } else if (chunk < 16) {
            const float* src = inputs + ((size_t)b * C_ + (cg0 - 128 + tc)) * L_;
            for (int j = tj; j < 130; j += 16) {
                int cj = conn_s[j];
                feat_s[tc][j] = (cj >= 0) ? src[cj] : 0.f;
            }
        } else if (tc < POS_) {
            const float sc = (float)(1 << tc);
            for (int j = tj; j < 130; j += 16) {
                int cj = conn_s[j];
                int lg = l0 - 1 + j;
                float v = 0.f;
                if (cj >= 0) v = sinf((sc * (float)(lg - cj)) / 1000.0f);
                feat_s[tc][j] = v;
            }
        }
        __syncthreads();
        for (int c = 0; c < CN; ++c) {
            float f[10];
            float4 fa = *(const float4*)&feat_s[c][ll];
            float4 fb = *(const float4*)&feat_s[c][ll + 4];
            float2 fc2 = *(const float2*)&feat_s[c][ll + 8];
            f[0]=fa.x; f[1]=fa.y; f[2]=fa.z; f[3]=fa.w;
            f[4]=fb.x; f[5]=fb.y; f[6]=fb.z; f[7]=fb.w;
            f[8]=fc2.x; f[9]=fc2.y;
            #pragma unroll
            for (int k = 0; k < 3; ++k) {
                const float* wrow = &Ws[c * 3 + k][o0];
                float4 wa = *(const float4*)&wrow[0];
                float4 wb = *(const float4*)&wrow[4];
                float w[8] = {wa.x, wa.y, wa.z, wa.w, wb.x, wb.y, wb.z, wb.w};
                #pragma unroll
                for (int oi = 0; oi < 8; ++oi)
                    #pragma unroll
                    for (int li = 0; li < 8; ++li)
                        acc[oi][li] = fmaf(w[oi], f[li + k], acc[oi][li]);
            }
        }
    }
    const int mflag = mflag_p[0];
    const int lbase = l0 + ll;
    float mv[8];
    #pragma unroll
    for (int li = 0; li < 8; ++li) {
        int idx = b * L_ + lbase + li;
        if (mflag == 1)      mv[li] = mask[idx] ? 1.f : 0.f;
        else if (mflag == 0) mv[li] = ((const int*)mask)[idx] ? 1.f : 0.f;
        else                 mv[li] = ((const int*)mask)[2 * idx] ? 1.f : 0.f;
    }
    #pragma unroll
    for (int oi = 0; oi < 8; ++oi) {
        float bo = bias[o0 + oi];
        float* dst = out + ((size_t)b * O_ + o0 + oi) * L_ + lbase;
        #pragma unroll
        for (int li = 0; li < 8; ++li) dst[li] = (acc[oi][li] + bo) * mv[li];
    }
}

extern "C" void kernel_launch(void* const* d_in, const int* in_sizes, int n_in,
                              void* d_out, int out_size, void* d_ws, size_t ws_size,
                              hipStream_t stream) {
    const float*         inputs = (const float*)d_in[0];
    const int*           conn   = (const int*)d_in[1];
    const unsigned char* mask   = (const unsigned char*)d_in[2];
    const float*         W      = (const float*)d_in[3];
    const float*         bias   = (const float*)d_in[4];
    float*               out    = (float*)d_out;

    const size_t g_bytes  = G_ELEMS * sizeof(_Float16);    // 16.78 MB
    const size_t wt_bytes = WT_ELEMS * sizeof(_Float16);   // 221 KB
    const size_t need     = g_bytes + wt_bytes + 64;

    if (ws_size < need) {
        int* mflag = (int*)d_ws;
        detect_kernel<<<1, 256, 0, stream>>>((const uint4*)mask, mflag);
        dim3 grid(L_ / 128, B_);
        cc_fallback_kernel<<<grid, 256, 0, stream>>>(inputs, conn, mask, W, bias, out, mflag);
        return;
    }

    _Float16* G     = (_Float16*)d_ws;
    _Float16* Wt2   = (_Float16*)((char*)d_ws + g_bytes);
    int*      mflag = (int*)((char*)d_ws + g_bytes + wt_bytes);

    prep_kernel<<<2481, 256, 0, stream>>>(inputs, W, (const uint4*)mask, G, Wt2, mflag);
    k2_gemm<<<512, 256, 0, stream>>>(G, Wt2, conn, mask, bias, out, mflag);
}

// Round 17
// 45.236 us; speedup vs baseline: 1.0909x; 1.0909x over previous
//
#include <hip/hip_runtime.h>
#include <math.h>

#define B_    8
#define C_    128
#define L_    8192
#define O_    128
#define POS_  10
#define CHIN  798
#define CH_   266          // 128 direct + 128 gathered + 10 penc
#define GSTR  128          // G row stride (direct channels only)
#define NCH   9            // chunks of 32 channels (288 padded)
#define TL2   128          // l-tile for GEMM (512 blocks -> 2 resident/CU)
#define G_ELEMS  ((size_t)B_ * L_ * GSTR)     // f16: 16.78 MB
#define WT_ELEMS ((size_t)3 * NCH * O_ * 32)  // f16: 221 KB

typedef _Float16 half8 __attribute__((ext_vector_type(8)));
typedef short short8 __attribute__((ext_vector_type(8)));
typedef float f32x4  __attribute__((ext_vector_type(4)));

// ---------------------------------------------------------------------------
// mask dtype detect core: 256 threads scan 64 KB; mflag 1=byte,0=i32,2=i64
// ---------------------------------------------------------------------------
__device__ __forceinline__ void detect_core(const uint4* __restrict__ m,
                                            int* __restrict__ mflag, int tid) {
    __shared__ int s[2];
    if (tid < 2) s[tid] = 0;
    __syncthreads();
    unsigned sub = 0, mid = 0;
    #pragma unroll
    for (int k = 0; k < 16; ++k) {
        uint4 w = m[tid + k * 256];              // 4096 * 16B = 64 KB
        sub |= (w.x | w.y | w.z | w.w) & 0xFFFFFF00u;
        mid |= (w.y | w.w) & 0x000000FFu;
    }
    unsigned long long bs = __ballot(sub != 0);
    unsigned long long bm = __ballot(mid != 0);
    if ((tid & 63) == 0) {
        if (bs) atomicOr(&s[0], 1);
        if (bm) atomicOr(&s[1], 1);
    }
    __syncthreads();
    if (tid == 0) mflag[0] = s[0] ? 1 : (s[1] ? 0 : 2);
}

__global__ void detect_kernel(const uint4* __restrict__ m, int* __restrict__ mflag) {
    detect_core(m, mflag, threadIdx.x);
}

// ---------------------------------------------------------------------------
// prep: blocks [0,2048): transpose inputs[b,c,l] f32 -> G[b,l,c] f16 (c<128)
//       blocks [2048,2480): Wt2[t][ch][o][cc] = (f16) W[o][3*(ch*32+cc)+t]
//       block 2480: mask dtype detect
// ---------------------------------------------------------------------------
__global__ __launch_bounds__(256, 4)
void prep_kernel(const float* __restrict__ inputs, const float* __restrict__ W,
                 const uint4* __restrict__ maskv,
                 _Float16* __restrict__ G, _Float16* __restrict__ Wt2,
                 int* __restrict__ mflag) {
    __shared__ float tile[64][65];
    const int bid = blockIdx.x;
    const int tid = threadIdx.x;

    if (bid == 2480) { detect_core(maskv, mflag, tid); return; }

    if (bid >= 2048) {   // Wt2 prep: 432 blocks * 256 = 110,592 elems exact
        int idx = (bid - 2048) * 256 + tid;
        int cc  = idx & 31;
        int o   = (idx >> 5) & 127;
        int tch = idx >> 12;          // 0..26
        int ch  = tch % 9;
        int t   = tch / 9;
        int cg  = ch * 32 + cc;
        Wt2[idx] = (cg < CH_) ? (_Float16)W[o * CHIN + 3 * cg + t] : (_Float16)0.f;
        return;
    }

    const int b  = bid & 7;          // b -> XCD affinity
    const int r  = bid >> 3;
    const int c0 = (r & 1) * 64;
    const int l0 = (r >> 1) * 64;
    const int ty = tid >> 6, tx = tid & 63;

    #pragma unroll
    for (int it = 0; it < 16; ++it) {
        int cl = it * 4 + ty;
        tile[cl][tx] = inputs[((size_t)(b * C_ + c0 + cl)) * L_ + l0 + tx];
    }
    __syncthreads();
    const int cp = (tid & 31) * 2;
    const int lr = tid >> 5;          // 0..7
    #pragma unroll
    for (int it = 0; it < 8; ++it) {
        int ll = it * 8 + lr;
        _Float16 pair[2] = {(_Float16)tile[cp][ll], (_Float16)tile[cp + 1][ll]};
        *(unsigned*)&G[((size_t)(b * L_ + l0 + ll)) * GSTR + c0 + cp] = *(unsigned*)pair;
    }
}

// ---------------------------------------------------------------------------
// K2: f16 MFMA GEMM. grid 512 flat (b = bid&7 -> XCD; 2 blocks/CU). 256 thr =
// 4 waves (2o x 2l), wave tile 64o x 64l.
// BOTH operands LDS double-buffered; ONE barrier per chunk (T3 2-phase):
//   issue next-chunk global loads -> COMPUTE(cur) -> ds_write to cur^1 ->
//   barrier -> flip. Writes to cur^1 race-free (nobody reads it this phase).
// A layout folds taps into the row: As[buf][o][t*32+c], 208B row (16B-aligned).
// ch 0-3: direct G rows; 4-7: G[conn]; 8: inline sinf penc.
// LDS 74.5 KB -> 2 blocks/CU. __launch_bounds__(256): VGPR cap 256, no spill.
// ---------------------------------------------------------------------------
__global__ __launch_bounds__(256)
void k2_gemm(const _Float16* __restrict__ G, const _Float16* __restrict__ Wt2,
             const int* __restrict__ conn,
             const unsigned char* __restrict__ mask,
             const float* __restrict__ bias,
             float* __restrict__ out,
             const int* __restrict__ mflag_p) {
    __shared__ _Float16 As[2][128][104];  // [buf][o][t*32+c] 53.2 KB
    __shared__ _Float16 Bs[2][130][40];   // [buf][row][c]    20.8 KB
    __shared__ int conn_s[130];

    const int bid = blockIdx.x;           // 0..511
    const int b   = bid & 7;
    const int l0  = (bid >> 3) * TL2;
    const int tid  = threadIdx.x;
    const int wave = tid >> 6;            // 0..3
    const int lane = tid & 63;
    const int wo = wave & 1;
    const int wl = wave >> 1;
    const int g  = lane >> 4;
    const int ln = lane & 15;

    const _Float16* gb = G + (size_t)b * L_ * GSTR;

    for (int j = tid; j < TL2 + 2; j += 256) {
        int l_ = l0 - 1 + j;
        conn_s[j] = ((unsigned)l_ < (unsigned)L_) ? conn[b * L_ + l_] : 0;
    }

    // A: q in [0,1536): cb=q&3, o=(q>>2)&127, tp=q>>9 ; q = tid + k*256
    auto aloadg = [&](int ch, int q) -> short8 {
        int cb = q & 3, o = (q >> 2) & 127, tp = q >> 9;
        return *(const short8*)&Wt2[((size_t)((tp * NCH + ch) * O_ + o)) * 32 + cb * 8];
    };
    // B: q in [0,520): cb=q&3 (8-f16 block), j=q>>2 (row 0..129)
    auto bloadg = [&](int ch, int q) -> short8 {
        int cb = q & 3, j = q >> 2;
        int l_ = l0 - 1 + j;
        short8 v = (short8)0;
        if ((unsigned)l_ < (unsigned)L_) {
            if (ch < 4) {
                v = *(const short8*)&gb[(size_t)l_ * GSTR + ch * 32 + cb * 8];
            } else if (ch < 8) {
                int cj = conn_s[j];
                v = *(const short8*)&gb[(size_t)cj * GSTR + (ch - 4) * 32 + cb * 8];
            } else if (cb < 2) {
                float d = (float)(l_ - conn_s[j]);
                _Float16 h[8];
                #pragma unroll
                for (int e = 0; e < 8; ++e) {
                    int p = cb * 8 + e;
                    h[e] = (p < POS_) ? (_Float16)sinf(((float)(1 << p)) * d / 1000.0f)
                                      : (_Float16)0.f;
                }
                v = *(short8*)h;
            }
        }
        return v;
    };

#define ALOADG(CH) { a0 = aloadg((CH), tid);        a1 = aloadg((CH), tid + 256); \
                     a2 = aloadg((CH), tid + 512);  a3 = aloadg((CH), tid + 768); \
                     a4 = aloadg((CH), tid + 1024); a5 = aloadg((CH), tid + 1280); }

#define AWR1(V, Q, BUF) { int cb_ = (Q) & 3, o_ = ((Q) >> 2) & 127, tp_ = (Q) >> 9; \
        *(short8*)&As[BUF][o_][tp_ * 32 + cb_ * 8] = V; }

#define AWR(BUF) { AWR1(a0, tid, BUF) AWR1(a1, tid + 256, BUF) \
                   AWR1(a2, tid + 512, BUF) AWR1(a3, tid + 768, BUF) \
                   AWR1(a4, tid + 1024, BUF) AWR1(a5, tid + 1280, BUF) }

#define BLOADG(CH) { s0 = bloadg((CH), tid); s1 = bloadg((CH), tid + 256); \
        if (tid < 8) s2 = bloadg((CH), 512 + tid); }

#define BWR1(V, Q, BUF) { int cb_ = (Q) & 3, j_ = (Q) >> 2; \
        *(short8*)&Bs[BUF][j_][cb_ * 8] = V; }

#define BWR(BUF) { BWR1(s0, tid, BUF) BWR1(s1, tid + 256, BUF) \
        if (tid < 8) { BWR1(s2, 512 + tid, BUF) } }

#define COMPUTE(BUF) { _Pragma("unroll") for (int t_ = 0; t_ < 3; ++t_) { \
        half8 bf_[4]; \
        _Pragma("unroll") for (int n_ = 0; n_ < 4; ++n_) \
            bf_[n_] = *(const half8*)&Bs[BUF][wl * 64 + n_ * 16 + ln + t_][8 * g]; \
        _Pragma("unroll") for (int m_ = 0; m_ < 4; ++m_) { \
            half8 af_ = *(const half8*)&As[BUF][wo * 64 + m_ * 16 + ln][t_ * 32 + 8 * g]; \
            _Pragma("unroll") for (int n_ = 0; n_ < 4; ++n_) \
                acc[m_][n_] = __builtin_amdgcn_mfma_f32_16x16x32_f16(af_, bf_[n_], acc[m_][n_], 0, 0, 0); } } }

    f32x4 acc[4][4];
    #pragma unroll
    for (int m = 0; m < 4; ++m)
        #pragma unroll
        for (int n = 0; n < 4; ++n) acc[m][n] = (f32x4)0.f;

    short8 a0, a1, a2, a3, a4, a5, s0, s1, s2;

    // prologue: stage chunk 0 into buf 0 (direct rows, no conn dependency)
    ALOADG(0); BLOADG(0);
    AWR(0); BWR(0);
    __syncthreads();   // publishes buf0 and conn_s

    // main loop: pairs of chunks, ONE barrier per chunk
    for (int ch = 0; ch < 8; ch += 2) {
        // chunk ch (buf 0)
        ALOADG(ch + 1); BLOADG(ch + 1);
        COMPUTE(0);
        AWR(1); BWR(1);
        __syncthreads();

        // chunk ch+1 (buf 1)
        ALOADG(ch + 2); BLOADG(ch + 2);     // ch+2 <= 8 always
        COMPUTE(1);
        AWR(0); BWR(0);
        __syncthreads();
    }
    COMPUTE(0);                             // chunk 8 (penc)

    // epilogue: D col = lane&15 (l), row = g*4+r (o) within frag
    const int mflag = mflag_p[0];
    float mv[4];
    #pragma unroll
    for (int n = 0; n < 4; ++n) {
        int l = l0 + wl * 64 + n * 16 + ln;
        int idx = b * L_ + l;
        if (mflag == 1)      mv[n] = mask[idx] ? 1.f : 0.f;
        else if (mflag == 0) mv[n] = ((const int*)mask)[idx] ? 1.f : 0.f;
        else                 mv[n] = ((const int*)mask)[2 * idx] ? 1.f : 0.f;
    }
    #pragma unroll
    for (int m = 0; m < 4; ++m) {
        #pragma unroll
        for (int r = 0; r < 4; ++r) {
            int o = wo * 64 + m * 16 + g * 4 + r;
            float bo = bias[o];
            #pragma unroll
            for (int n = 0; n < 4; ++n) {
                int l = l0 + wl * 64 + n * 16 + ln;
                out[((size_t)(b * O_ + o)) * L_ + l] = (acc[m][n][r] + bo) * mv[n];
            }
        }
    }
#undef ALOADG
#undef AWR1
#undef AWR
#undef BLOADG
#undef BWR1
#undef BWR
#undef COMPUTE
}

// ---------------------------------------------------------------------------
// Fallback (fp32 vector path) if workspace too small
// ---------------------------------------------------------------------------
__global__ __launch_bounds__(256, 2)
void cc_fallback_kernel(const float* __restrict__ inputs,
                        const int* __restrict__ conn,
                        const unsigned char* __restrict__ mask,
                        const float* __restrict__ W,
                        const float* __restrict__ bias,
                        float* __restrict__ out,
                        const int* __restrict__ mflag_p) {
    __shared__ int   conn_s[130];
    __shared__ float feat_s[16][132];
    __shared__ float Ws[48][136];

    const int b   = blockIdx.y;
    const int l0  = blockIdx.x * 128;
    const int tid = threadIdx.x;
    const int ot  = tid >> 4;
    const int lt  = tid & 15;
    const int o0  = ot * 8;
    const int ll  = lt * 8;

    for (int j = tid; j < 130; j += 256) {
        int lg = l0 - 1 + j;
        conn_s[j] = ((unsigned)lg < (unsigned)L_) ? conn[b * L_ + lg] : -1;
    }
    float acc[8][8];
    #pragma unroll
    for (int i = 0; i < 8; ++i)
        #pragma unroll
        for (int j = 0; j < 8; ++j) acc[i][j] = 0.f;

    const int tc = ot, tj = lt;
    for (int chunk = 0; chunk < 17; ++chunk) {
        const int CN  = (chunk < 16) ? 16 : POS_;
        const int cg0 = chunk * 16;
        const int col0 = 3 * cg0;
        __syncthreads();
        {
            const int nw = O_ * CN * 3;
            for (int idx = tid; idx < nw; idx += 256) {
                int o = idx & 127, kk = idx >> 7;
                Ws[kk][o] = W[o * CHIN + col0 + kk];
            }
        }
        if (chunk < 8) {
            const float* src = inputs + ((size_t)b * C_ + (cg0 + tc)) * L_;
            for (int j = tj; j < 130; j += 16) {
                int lg = l0 - 1 + j;
                feat_s[tc][j] = ((unsigned)lg < (unsigned)L_) ? src[lg] : 0.f;
            }
        } else if (chunk < 16) {
            const float* src = inputs + ((size_t)b * C_ + (cg0 - 128 + tc)) * L_;
            for (int j = tj; j < 130; j += 16) {
                int cj = conn_s[j];
                feat_s[tc][j] = (cj >= 0) ? src[cj] : 0.f;
            }
        } else if (tc < POS_) {
            const float sc = (float)(1 << tc);
            for (int j = tj; j < 130; j += 16) {
                int cj = conn_s[j];
                int lg = l0 - 1 + j;
                float v = 0.f;
                if (cj >= 0) v = sinf((sc * (float)(lg - cj)) / 1000.0f);
                feat_s[tc][j] = v;
            }
        }
        __syncthreads();
        for (int c = 0; c < CN; ++c) {
            float f[10];
            float4 fa = *(const float4*)&feat_s[c][ll];
            float4 fb = *(const float4*)&feat_s[c][ll + 4];
            float2 fc2 = *(const float2*)&feat_s[c][ll + 8];
            f[0]=fa.x; f[1]=fa.y; f[2]=fa.z; f[3]=fa.w;
            f[4]=fb.x; f[5]=fb.y; f[6]=fb.z; f[7]=fb.w;
            f[8]=fc2.x; f[9]=fc2.y;
            #pragma unroll
            for (int k = 0; k < 3; ++k) {
                const float* wrow = &Ws[c * 3 + k][o0];
                float4 wa = *(const float4*)&wrow[0];
                float4 wb = *(const float4*)&wrow[4];
                float w[8] = {wa.x, wa.y, wa.z, wa.w, wb.x, wb.y, wb.z, wb.w};
                #pragma unroll
                for (int oi = 0; oi < 8; ++oi)
                    #pragma unroll
                    for (int li = 0; li < 8; ++li)
                        acc[oi][li] = fmaf(w[oi], f[li + k], acc[oi][li]);
            }
        }
    }
    const int mflag = mflag_p[0];
    const int lbase = l0 + ll;
    float mv[8];
    #pragma unroll
    for (int li = 0; li < 8; ++li) {
        int idx = b * L_ + lbase + li;
        if (mflag == 1)      mv[li] = mask[idx] ? 1.f : 0.f;
        else if (mflag == 0) mv[li] = ((const int*)mask)[idx] ? 1.f : 0.f;
        else                 mv[li] = ((const int*)mask)[2 * idx] ? 1.f : 0.f;
    }
    #pragma unroll
    for (int oi = 0; oi < 8; ++oi) {
        float bo = bias[o0 + oi];
        float* dst = out + ((size_t)b * O_ + o0 + oi) * L_ + lbase;
        #pragma unroll
        for (int li = 0; li < 8; ++li) dst[li] = (acc[oi][li] + bo) * mv[li];
    }
}

extern "C" void kernel_launch(void* const* d_in, const int* in_sizes, int n_in,
                              void* d_out, int out_size, void* d_ws, size_t ws_size,
                              hipStream_t stream) {
    const float*         inputs = (const float*)d_in[0];
    const int*           conn   = (const int*)d_in[1];
    const unsigned char* mask   = (const unsigned char*)d_in[2];
    const float*         W      = (const float*)d_in[3];
    const float*         bias   = (const float*)d_in[4];
    float*               out    = (float*)d_out;

    const size_t g_bytes  = G_ELEMS * sizeof(_Float16);    // 16.78 MB
    const size_t wt_bytes = WT_ELEMS * sizeof(_Float16);   // 221 KB
    const size_t need     = g_bytes + wt_bytes + 64;

    if (ws_size < need) {
        int* mflag = (int*)d_ws;
        detect_kernel<<<1, 256, 0, stream>>>((const uint4*)mask, mflag);
        dim3 grid(L_ / 128, B_);
        cc_fallback_kernel<<<grid, 256, 0, stream>>>(inputs, conn, mask, W, bias, out, mflag);
        return;
    }

    _Float16* G     = (_Float16*)d_ws;
    _Float16* Wt2   = (_Float16*)((char*)d_ws + g_bytes);
    int*      mflag = (int*)((char*)d_ws + g_bytes + wt_bytes);

    prep_kernel<<<2481, 256, 0, stream>>>(inputs, W, (const uint4*)mask, G, Wt2, mflag);
    k2_gemm<<<512, 256, 0, stream>>>(G, Wt2, conn, mask, bias, out, mflag);
}